// Round 3
// baseline (662842.627 us; speedup 1.0000x reference)
//
#include <hip/hip_runtime.h>
#include <hip/hip_bf16.h>

// ESN recurrence, B=16 T=512 F=512 H=2048 V=64.
// Integer matvecs exact (int4 packed, v_dot8_i32_i4). FP path replicates
// XLA/Eigen f32 tanh. 16 slice-WGs per batch exchange h as tagged 8B units
// {data,tag}: one coherence round trip per step. If the whole batch group
// sits on one XCD (runtime-verified via HW_REG_XCC_ID), exchange runs through
// the shared per-XCD L2 (plain store + sc0 load); otherwise agent-scope
// atomics (L3). Weights pinned in VGPRs via opaque asm. Readout deferred.

#define B_ 16
#define T_ 512
#define F_ 512
#define H_ 2048
#define V_ 64
#define SLICES 16
#define RPW 128
#define NTHREADS 256
#define NWG 256

#if defined(__has_builtin)
#if __has_builtin(__builtin_amdgcn_sdot8)
#define HAVE_SDOT8 1
#endif
#endif

__device__ __forceinline__ int sdot8(int a, int b, int c) {
#ifdef HAVE_SDOT8
  return __builtin_amdgcn_sdot8(a, b, c, false);
#else
#pragma unroll
  for (int i = 0; i < 8; ++i) {
    int av = (a << (28 - 4 * i)) >> 28;
    int bv = (b << (28 - 4 * i)) >> 28;
    c += av * bv;
  }
  return c;
#endif
}

// XLA / Eigen generic_fast_tanh_float, f32, fma form.
__device__ __forceinline__ float tanh_ref(float x) {
  float ax = fabsf(x);
  float xc = fminf(fmaxf(x, -7.90531110763549805f), 7.90531110763549805f);
  float x2 = __fmul_rn(xc, xc);
  float p = -2.76076847742355e-16f;
  p = __fmaf_rn(x2, p, 2.00018790482477e-13f);
  p = __fmaf_rn(x2, p, -8.60467152213735e-11f);
  p = __fmaf_rn(x2, p, 5.12229709037114e-08f);
  p = __fmaf_rn(x2, p, 1.48572235717979e-05f);
  p = __fmaf_rn(x2, p, 6.37261928875436e-04f);
  p = __fmaf_rn(x2, p, 4.89352455891786e-03f);
  p = __fmul_rn(xc, p);
  float q = 1.19825839466702e-06f;
  q = __fmaf_rn(x2, q, 1.18534705686654e-04f);
  q = __fmaf_rn(x2, q, 2.26843463243900e-03f);
  q = __fmaf_rn(x2, q, 4.89352518554385e-03f);
  float r = __fdiv_rn(p, q);
  return (ax < 0.0004f) ? x : r;
}

__device__ __forceinline__ unsigned f2bf(float f) {  // f32 -> bf16 bits, RNE
  unsigned u = __float_as_uint(f);
  return (u + 0x7fffu + ((u >> 16) & 1u)) >> 16;
}

// tagged 8B exchange unit: low dword = packed h nibbles, high dword = step tag
__device__ __forceinline__ unsigned poll_tag(const unsigned long long* p, unsigned tag,
                                             bool fast) {
  unsigned long long u;
  if (fast) {
    int spins = 0;
    for (;;) {
      asm volatile("global_load_dwordx2 %0, %1, off sc0\n\ts_waitcnt vmcnt(0)"
                   : "=v"(u) : "v"(p) : "memory");
      if ((unsigned)(u >> 32) == tag) break;
      if (++spins > (1 << 14)) {  // escalation guard: fall back to coherent loads
        do {
          u = __hip_atomic_load(p, __ATOMIC_RELAXED, __HIP_MEMORY_SCOPE_AGENT);
        } while ((unsigned)(u >> 32) != tag);
        break;
      }
    }
  } else {
    do {
      u = __hip_atomic_load(p, __ATOMIC_RELAXED, __HIP_MEMORY_SCOPE_AGENT);
    } while ((unsigned)(u >> 32) != tag);
  }
  return (unsigned)u;
}

__device__ __forceinline__ void publish_tag(unsigned long long* p, unsigned data,
                                            unsigned tag, bool fast) {
  unsigned long long u = ((unsigned long long)tag << 32) | data;
  if (fast) {  // same-XCD: write-through L1 into the shared L2
    asm volatile("global_store_dwordx2 %0, %1, off sc0" :: "v"(p), "v"(u) : "memory");
  } else {
    __hip_atomic_store(p, u, __ATOMIC_RELAXED, __HIP_MEMORY_SCOPE_AGENT);
  }
}

// ---- prep: pack weights to int4 nibbles ------------------------------------
__global__ void pack_weights(const int* __restrict__ Wres, const int* __restrict__ Win,
                             int* __restrict__ wr4, int* __restrict__ wi4) {
  int id = blockIdx.x * blockDim.x + threadIdx.x;
  if (id < H_ * 256) {
    const int* src = Wres + id * 8;
    int pk = 0;
#pragma unroll
    for (int i = 0; i < 8; ++i) pk |= (src[i] & 15) << (4 * i);
    wr4[id] = pk;
  } else {
    int id2 = id - H_ * 256;
    if (id2 < H_ * 64) {
      const int* src = Win + id2 * 8;
      int pk = 0;
#pragma unroll
      for (int i = 0; i < 8; ++i) pk |= (src[i] & 15) << (4 * i);
      wi4[id2] = pk;
    }
  }
}

// ---- prep: quantize input, split u = 8*a + m into two int4 planes ----------
__global__ void pack_u(const float* __restrict__ x, int* __restrict__ um, int* __restrict__ ua) {
  int idx = blockIdx.x * blockDim.x + threadIdx.x;
  if (idx >= B_ * T_ * 64) return;
  const float* src = x + (size_t)idx * 8;
  int pm = 0, pa = 0;
#pragma unroll
  for (int i = 0; i < 8; ++i) {
    int u = (int)rintf(__fmul_rn(src[i], 3.0f));  // round-half-even == jnp.round
    int vv = u + 128;
    pm |= (vv & 7) << (4 * i);
    pa |= (((vv >> 3) - 16) & 15) << (4 * i);
  }
  um[idx] = pm;
  ua[idx] = pa;
}

// ---- main persistent kernel ------------------------------------------------
__global__ void __launch_bounds__(NTHREADS, 1) esn_main(
    const int* __restrict__ um, const int* __restrict__ ua,
    const int* __restrict__ wr4, const int* __restrict__ wi4,
    unsigned long long* hq2, int* xccbuf,
    const float* __restrict__ S_res, const float* __restrict__ S_in,
    const float* __restrict__ g_res, const float* __restrict__ g_in,
    unsigned* __restrict__ Hs, int t0, int t1) {
  __shared__ int lds_h4[256];
  __shared__ int lds_um[64];
  __shared__ int lds_ua[64];
  __shared__ int lds_xcc[16];

  const int wg = blockIdx.x;
  const int b = wg & 15, slice = wg >> 4;
  const int tid = threadIdx.x;
  const unsigned lane = tid & 63;
  const int wave = tid >> 6;
  const int half = tid & 1;
  const int grow = slice * RPW + (tid >> 1);

  // --- one-time XCD co-location check (persistent mode only) ---
  bool fast = false;
  if (t1 - t0 > 1) {
    int xcc = 0;
    asm volatile("s_getreg_b32 %0, hwreg(HW_REG_XCC_ID)" : "=s"(xcc));
    xcc &= 0xf;
    if (tid == 0)
      __hip_atomic_store(&xccbuf[b * 16 + slice], xcc + 1, __ATOMIC_RELAXED,
                         __HIP_MEMORY_SCOPE_AGENT);
    if (tid < 16) {
      int v;
      do {
        v = __hip_atomic_load(&xccbuf[b * 16 + tid], __ATOMIC_RELAXED,
                              __HIP_MEMORY_SCOPE_AGENT);
      } while (v == 0);
      lds_xcc[tid] = v;
    }
    __syncthreads();
    bool same = true;
#pragma unroll
    for (int i = 0; i < 16; ++i) same &= (lds_xcc[i] == lds_xcc[0]);
    fast = same;
  }

  // W_res slice rows -> registers, pinned via opaque asm (no remat/reload)
  ::int4 wreg[32];
  {
    const ::int4* gw = (const ::int4*)wr4;  // 64 int4 per row
#pragma unroll
    for (int m = 0; m < 32; ++m) wreg[m] = gw[grow * 64 + half * 32 + m];
  }
#pragma unroll
  for (int m = 0; m < 32; ++m)
    asm volatile("" : "+v"(wreg[m].x), "+v"(wreg[m].y), "+v"(wreg[m].z), "+v"(wreg[m].w));
  ::int4 rwm[8];
  {
    const ::int4* gwi = (const ::int4*)wi4;  // 16 int4 per row
#pragma unroll
    for (int m = 0; m < 8; ++m) rwm[m] = gwi[grow * 16 + half * 8 + m];
  }
#pragma unroll
  for (int m = 0; m < 8; ++m)
    asm volatile("" : "+v"(rwm[m].x), "+v"(rwm[m].y), "+v"(rwm[m].z), "+v"(rwm[m].w));

  const float sr = __fmul_rn(__fdiv_rn(S_res[grow], 49.0f), g_res[0]);
  const float si = __fmul_rn(__fdiv_rn(S_in[grow], 21.0f), g_in[0]);

  const ::int4* lh4 = (const ::int4*)lds_h4 + half * 32;
  const ::int4* lum4 = (const ::int4*)lds_um + half * 8;
  const ::int4* lua4 = (const ::int4*)lds_ua + half * 8;

  for (int t = t0; t < t1; ++t) {
    const int cur = t & 1, nxt = cur ^ 1;
    // stage u nibbles
    if (tid < 64)
      lds_um[tid] = um[(b * T_ + t) * 64 + tid];
    else if (tid < 128)
      lds_ua[tid - 64] = ua[(b * T_ + t) * 64 + (tid - 64)];
    __syncthreads();

    // input dot FIRST (independent of h) — off the post-arrival critical path
    int am = 0, aa = 0;
#pragma unroll
    for (int m = 0; m < 8; ++m) {
      ::int4 w = rwm[m];
      ::int4 uM = lum4[m];
      ::int4 uA = lua4[m];
      am = sdot8(w.x, uM.x, am); am = sdot8(w.y, uM.y, am);
      am = sdot8(w.z, uM.z, am); am = sdot8(w.w, uM.w, am);
      aa = sdot8(w.x, uA.x, aa); aa = sdot8(w.y, uA.y, aa);
      aa = sdot8(w.z, uA.z, aa); aa = sdot8(w.w, uA.w, aa);
    }
    int accin = am + (aa << 3);
    accin += __shfl_xor(accin, 1);

    // single-round-trip tagged poll for h_t
    unsigned hd = poll_tag(hq2 + ((size_t)(cur * 16 + b) * 256 + tid), (unsigned)t, fast);
    lds_h4[tid] = (int)hd;
    __syncthreads();

    // recurrent dot from pinned registers x LDS-broadcast h
    int acc = 0;
#pragma unroll
    for (int m = 0; m < 32; ++m) {
      ::int4 h = lh4[m];
      acc = sdot8(wreg[m].x, h.x, acc);
      acc = sdot8(wreg[m].y, h.y, acc);
      acc = sdot8(wreg[m].z, h.z, acc);
      acc = sdot8(wreg[m].w, h.w, acc);
    }
    acc += __shfl_xor(acc, 1);

    int cr = min(max(acc, -32768), 32767);
    int ci = min(max(accin, -32768), 32767);
    float arg = __fadd_rn(__fmul_rn((float)cr, sr), __fmul_rn((float)ci, si));
    float hn = tanh_ref(arg);
    float hc = fminf(fmaxf(hn, -1.0f), 1.0f);
    int qv = (int)rintf(__fmul_rn(hc, 7.0f));

    // in-wave nibble pack (8 rows -> 1 dword), publish ASAP
    unsigned nib = ((unsigned)qv & 15u) << (4 * ((lane >> 1) & 7));
    nib |= (unsigned)__shfl_xor((int)nib, 1);
    nib |= (unsigned)__shfl_xor((int)nib, 2);
    nib |= (unsigned)__shfl_xor((int)nib, 4);
    nib |= (unsigned)__shfl_xor((int)nib, 8);
    if ((lane & 15) == 0)
      publish_tag(hq2 + ((size_t)(nxt * 16 + b) * 256 + slice * 16 + wave * 4 + (lane >> 4)),
                  nib, (unsigned)(t + 1), fast);

    // bf16 h history for deferred readout
    unsigned bfb = f2bf(hn);
    unsigned other = (unsigned)__shfl_xor((int)bfb, 2);
    if ((tid & 3) == 0)
      Hs[(size_t)(b * T_ + t) * (H_ / 2) + slice * 64 + (tid >> 2)] = bfb | (other << 16);
  }
}

// ---- deferred readout: 512 blocks x 256 thr; 16 bt-rows x 64 v per block ---
#define ACC8(acc, p, w0, w1)                                    \
  acc = fmaf(__uint_as_float(p.x << 16), w0.x, acc);            \
  acc = fmaf(__uint_as_float(p.x & 0xffff0000u), w0.y, acc);    \
  acc = fmaf(__uint_as_float(p.y << 16), w0.z, acc);            \
  acc = fmaf(__uint_as_float(p.y & 0xffff0000u), w0.w, acc);    \
  acc = fmaf(__uint_as_float(p.z << 16), w1.x, acc);            \
  acc = fmaf(__uint_as_float(p.z & 0xffff0000u), w1.y, acc);    \
  acc = fmaf(__uint_as_float(p.w << 16), w1.z, acc);            \
  acc = fmaf(__uint_as_float(p.w & 0xffff0000u), w1.w, acc);

__global__ void __launch_bounds__(256) readout(const unsigned* __restrict__ Hs,
                                               const float* __restrict__ Wout,
                                               const float* __restrict__ Wb,
                                               float* __restrict__ out) {
  const int v = threadIdx.x & 63;
  const int rg = threadIdx.x >> 6;              // 0..3
  const int bt0 = blockIdx.x * 16 + rg * 4;     // 4 consecutive bt rows
  const float* wrow = Wout + (size_t)v * H_;
  const unsigned* h0 = Hs + (size_t)bt0 * (H_ / 2);
  float a0 = Wb[v], a1 = a0, a2 = a0, a3 = a0;
  for (int j = 0; j < H_ / 2; j += 4) {
    float4 w0 = *(const float4*)(wrow + 2 * j);
    float4 w1 = *(const float4*)(wrow + 2 * j + 4);
    uint4 p0 = *(const uint4*)(h0 + j);
    uint4 p1 = *(const uint4*)(h0 + (H_ / 2) + j);
    uint4 p2 = *(const uint4*)(h0 + 2 * (H_ / 2) + j);
    uint4 p3 = *(const uint4*)(h0 + 3 * (H_ / 2) + j);
    ACC8(a0, p0, w0, w1)
    ACC8(a1, p1, w0, w1)
    ACC8(a2, p2, w0, w1)
    ACC8(a3, p3, w0, w1)
  }
  out[(size_t)(bt0 + 0) * V_ + v] = a0;
  out[(size_t)(bt0 + 1) * V_ + v] = a1;
  out[(size_t)(bt0 + 2) * V_ + v] = a2;
  out[(size_t)(bt0 + 3) * V_ + v] = a3;
}

extern "C" void kernel_launch(void* const* d_in, const int* in_sizes, int n_in,
                              void* d_out, int out_size, void* d_ws, size_t ws_size,
                              hipStream_t stream) {
  const float* x = (const float*)d_in[0];
  const float* S_res = (const float*)d_in[1];
  const float* S_in = (const float*)d_in[2];
  const float* g_res = (const float*)d_in[3];
  const float* g_in = (const float*)d_in[4];
  const float* Woutw = (const float*)d_in[5];
  const float* Woutb = (const float*)d_in[6];
  const int* Wres = (const int*)d_in[7];
  const int* Win = (const int*)d_in[8];

  char* ws = (char*)d_ws;
  int* xccbuf = (int*)ws;                                    // 1 KiB
  unsigned long long* hq2 = (unsigned long long*)(ws + 4096);  // 64 KiB tagged h
  int* um = (int*)(ws + (1 << 20));                          // 2 MiB
  int* ua = um + (1 << 19);                                  // 2 MiB
  int* wr4 = ua + (1 << 19);                                 // 2 MiB
  int* wi4 = wr4 + (1 << 19);                                // 512 KiB
  unsigned* Hs = (unsigned*)(ws + (8 << 20));                // 32 MiB bf16 h history

  hipMemsetAsync(d_ws, 0, 4096 + 65536, stream);  // xccbuf + hq2 (h0=0, tag0=0)
  hipLaunchKernelGGL(pack_weights, dim3(2560), dim3(256), 0, stream, Wres, Win, wr4, wi4);
  hipLaunchKernelGGL(pack_u, dim3(2048), dim3(256), 0, stream, x, um, ua);

  float* outf = (float*)d_out;
  int t0 = 0, t1 = T_;
  void* args[] = {&um, &ua, &wr4, &wi4, &hq2, &xccbuf, &S_res, &S_in,
                  &g_res, &g_in, &Hs, &t0, &t1};
  hipError_t e = hipLaunchCooperativeKernel((const void*)esn_main, dim3(NWG), dim3(NTHREADS),
                                            args, 0, stream);
  if (e != hipSuccess) {
    // fallback: one launch per timestep (kernel boundary = sync; fast=false)
    for (int t = 0; t < T_; ++t) {
      hipLaunchKernelGGL(esn_main, dim3(NWG), dim3(NTHREADS), 0, stream,
                         um, ua, wr4, wi4, hq2, xccbuf, S_res, S_in, g_res, g_in, Hs, t, t + 1);
    }
  }
  hipLaunchKernelGGL(readout, dim3(B_ * T_ / 16), dim3(256), 0, stream,
                     Hs, Woutw, Woutb, outf);
}

// Round 4
// 1118.008 us; speedup vs baseline: 592.8785x; 592.8785x over previous
//
#include <hip/hip_runtime.h>
#include <hip/hip_bf16.h>

// ESN recurrence, B=16 T=512 F=512 H=2048 V=64.
// Integer matvecs exact (int4 packed, v_dot8_i32_i4). FP path replicates
// XLA/Eigen f32 tanh. W_res slice lives in LDS (conflict-free transposed
// layout, on-chip guaranteed). 16 slice-WGs per batch exchange h as tagged
// 8B {data,tag} units via relaxed agent-scope atomics: one L3 round trip per
// step. Readout deferred to a separate GEMM kernel.

#define B_ 16
#define T_ 512
#define F_ 512
#define H_ 2048
#define V_ 64
#define SLICES 16
#define RPW 128
#define NTHREADS 256
#define NWG 256

#if defined(__has_builtin)
#if __has_builtin(__builtin_amdgcn_sdot8)
#define HAVE_SDOT8 1
#endif
#endif

__device__ __forceinline__ int sdot8(int a, int b, int c) {
#ifdef HAVE_SDOT8
  return __builtin_amdgcn_sdot8(a, b, c, false);
#else
#pragma unroll
  for (int i = 0; i < 8; ++i) {
    int av = (a << (28 - 4 * i)) >> 28;
    int bv = (b << (28 - 4 * i)) >> 28;
    c += av * bv;
  }
  return c;
#endif
}

// XLA / Eigen generic_fast_tanh_float, f32, fma form (bit-matching matters:
// quantized recurrence is chaotic at ULP level).
__device__ __forceinline__ float tanh_ref(float x) {
  float ax = fabsf(x);
  float xc = fminf(fmaxf(x, -7.90531110763549805f), 7.90531110763549805f);
  float x2 = __fmul_rn(xc, xc);
  float p = -2.76076847742355e-16f;
  p = __fmaf_rn(x2, p, 2.00018790482477e-13f);
  p = __fmaf_rn(x2, p, -8.60467152213735e-11f);
  p = __fmaf_rn(x2, p, 5.12229709037114e-08f);
  p = __fmaf_rn(x2, p, 1.48572235717979e-05f);
  p = __fmaf_rn(x2, p, 6.37261928875436e-04f);
  p = __fmaf_rn(x2, p, 4.89352455891786e-03f);
  p = __fmul_rn(xc, p);
  float q = 1.19825839466702e-06f;
  q = __fmaf_rn(x2, q, 1.18534705686654e-04f);
  q = __fmaf_rn(x2, q, 2.26843463243900e-03f);
  q = __fmaf_rn(x2, q, 4.89352518554385e-03f);
  float r = __fdiv_rn(p, q);
  return (ax < 0.0004f) ? x : r;
}

__device__ __forceinline__ unsigned f2bf(float f) {  // f32 -> bf16 bits, RNE
  unsigned u = __float_as_uint(f);
  return (u + 0x7fffu + ((u >> 16) & 1u)) >> 16;
}

// tagged 8B exchange unit: low dword = packed h nibbles, high dword = step tag
__device__ __forceinline__ unsigned poll_tag(const unsigned long long* p, unsigned tag) {
  unsigned long long u;
  do {
    u = __hip_atomic_load(p, __ATOMIC_RELAXED, __HIP_MEMORY_SCOPE_AGENT);
  } while ((unsigned)(u >> 32) != tag);
  return (unsigned)u;
}

__device__ __forceinline__ void publish_tag(unsigned long long* p, unsigned data, unsigned tag) {
  unsigned long long u = ((unsigned long long)tag << 32) | data;
  __hip_atomic_store(p, u, __ATOMIC_RELAXED, __HIP_MEMORY_SCOPE_AGENT);
}

// ---- prep: pack weights to int4 nibbles ------------------------------------
__global__ void pack_weights(const int* __restrict__ Wres, const int* __restrict__ Win,
                             int* __restrict__ wr4, int* __restrict__ wi4) {
  int id = blockIdx.x * blockDim.x + threadIdx.x;
  if (id < H_ * 256) {
    const int* src = Wres + id * 8;
    int pk = 0;
#pragma unroll
    for (int i = 0; i < 8; ++i) pk |= (src[i] & 15) << (4 * i);
    wr4[id] = pk;
  } else {
    int id2 = id - H_ * 256;
    if (id2 < H_ * 64) {
      const int* src = Win + id2 * 8;
      int pk = 0;
#pragma unroll
      for (int i = 0; i < 8; ++i) pk |= (src[i] & 15) << (4 * i);
      wi4[id2] = pk;
    }
  }
}

// ---- prep: quantize input, split u = 8*a + m into two int4 planes ----------
__global__ void pack_u(const float* __restrict__ x, int* __restrict__ um, int* __restrict__ ua) {
  int idx = blockIdx.x * blockDim.x + threadIdx.x;
  if (idx >= B_ * T_ * 64) return;
  const float* src = x + (size_t)idx * 8;
  int pm = 0, pa = 0;
#pragma unroll
  for (int i = 0; i < 8; ++i) {
    int u = (int)rintf(__fmul_rn(src[i], 3.0f));  // round-half-even == jnp.round
    int vv = u + 128;
    pm |= (vv & 7) << (4 * i);
    pa |= (((vv >> 3) - 16) & 15) << (4 * i);
  }
  um[idx] = pm;
  ua[idx] = pa;
}

// ---- main persistent kernel ------------------------------------------------
// WG = (batch b = wg&15, slice = wg>>4). W_res slice in LDS, transposed
// layout lw4[m*256+tid]: every wave ds_read_b128 is lane-contiguous 1KiB
// (conflict-free). h broadcast via LDS (2-way, free). u double-buffered in
// registers. Tagged 8B agent-atomic exchange, one round trip per step.
__global__ void __launch_bounds__(NTHREADS, 1) esn_main(
    const int* __restrict__ um, const int* __restrict__ ua,
    const int* __restrict__ wr4, const int* __restrict__ wi4,
    unsigned long long* hq2,
    const float* __restrict__ S_res, const float* __restrict__ S_in,
    const float* __restrict__ g_res, const float* __restrict__ g_in,
    unsigned* __restrict__ Hs, int t0, int t1) {
  extern __shared__ char smem[];
  ::int4* lw4 = (::int4*)smem;                 // 8192 int4 = 128 KiB
  int* lds_h4 = (int*)(lw4 + 8192);            // 256 dw
  int* lds_um = lds_h4 + 256;                  // 64 dw
  int* lds_ua = lds_um + 64;                   // 64 dw

  const int wg = blockIdx.x;
  const int b = wg & 15, slice = wg >> 4;
  const int tid = threadIdx.x;
  const unsigned lane = tid & 63;
  const int wave = tid >> 6;
  const int half = tid & 1;
  const int grow = slice * RPW + (tid >> 1);

  // one-time: W_res slice -> LDS (transposed: chunk m of all threads adjacent)
  {
    const ::int4* gw = (const ::int4*)wr4;  // 64 int4 per row
#pragma unroll 4
    for (int m = 0; m < 32; ++m) lw4[m * 256 + tid] = gw[grow * 64 + half * 32 + m];
  }
  // W_in slice -> regs (small, stays resident)
  ::int4 rwm[8];
  {
    const ::int4* gwi = (const ::int4*)wi4;  // 16 int4 per row
#pragma unroll
    for (int m = 0; m < 8; ++m) rwm[m] = gwi[grow * 16 + half * 8 + m];
  }
  const float sr = __fmul_rn(__fdiv_rn(S_res[grow], 49.0f), g_res[0]);
  const float si = __fmul_rn(__fdiv_rn(S_in[grow], 21.0f), g_in[0]);

  const ::int4* lh4 = (const ::int4*)lds_h4 + half * 32;
  const ::int4* lum4 = (const ::int4*)lds_um + half * 8;
  const ::int4* lua4 = (const ::int4*)lds_ua + half * 8;

  // prologue: u regs for t0
  unsigned ureg = 0;
  if (tid < 64)
    ureg = um[(b * T_ + t0) * 64 + tid];
  else if (tid < 128)
    ureg = ua[(b * T_ + t0) * 64 + (tid - 64)];

  for (int t = t0; t < t1; ++t) {
    const int cur = t & 1, nxt = cur ^ 1;
    // stage this step's u (from regs), covered by sync below
    if (tid < 64)
      lds_um[tid] = ureg;
    else if (tid < 128)
      lds_ua[tid - 64] = ureg;
    __syncthreads();  // also protects lds_h4 vs previous iteration's readers

    // prefetch next step's u into regs (overlaps everything below)
    unsigned unext = 0;
    if (t + 1 < t1) {
      if (tid < 64)
        unext = um[(b * T_ + t + 1) * 64 + tid];
      else if (tid < 128)
        unext = ua[(b * T_ + t + 1) * 64 + (tid - 64)];
    }

    // input dot FIRST (independent of h) — overlaps producer publish latency
    int am = 0, aa = 0;
#pragma unroll
    for (int m = 0; m < 8; ++m) {
      ::int4 w = rwm[m];
      ::int4 uM = lum4[m];
      ::int4 uA = lua4[m];
      am = sdot8(w.x, uM.x, am); am = sdot8(w.y, uM.y, am);
      am = sdot8(w.z, uM.z, am); am = sdot8(w.w, uM.w, am);
      aa = sdot8(w.x, uA.x, aa); aa = sdot8(w.y, uA.y, aa);
      aa = sdot8(w.z, uA.z, aa); aa = sdot8(w.w, uA.w, aa);
    }
    int accin = am + (aa << 3);
    accin += __shfl_xor(accin, 1);

    // single-round-trip tagged poll for h_t
    unsigned hd = poll_tag(hq2 + ((size_t)(cur * 16 + b) * 256 + tid), (unsigned)t);
    lds_h4[tid] = (int)hd;
    __syncthreads();

    // recurrent dot: conflict-free weight reads x broadcast h, 4 acc chains
    int c0 = 0, c1 = 0, c2 = 0, c3 = 0;
#pragma unroll
    for (int m = 0; m < 32; m += 4) {
      ::int4 w0 = lw4[(m + 0) * 256 + tid];
      ::int4 w1 = lw4[(m + 1) * 256 + tid];
      ::int4 w2 = lw4[(m + 2) * 256 + tid];
      ::int4 w3 = lw4[(m + 3) * 256 + tid];
      ::int4 h0 = lh4[m + 0];
      ::int4 h1 = lh4[m + 1];
      ::int4 h2 = lh4[m + 2];
      ::int4 h3 = lh4[m + 3];
      c0 = sdot8(w0.x, h0.x, c0); c0 = sdot8(w0.y, h0.y, c0);
      c0 = sdot8(w0.z, h0.z, c0); c0 = sdot8(w0.w, h0.w, c0);
      c1 = sdot8(w1.x, h1.x, c1); c1 = sdot8(w1.y, h1.y, c1);
      c1 = sdot8(w1.z, h1.z, c1); c1 = sdot8(w1.w, h1.w, c1);
      c2 = sdot8(w2.x, h2.x, c2); c2 = sdot8(w2.y, h2.y, c2);
      c2 = sdot8(w2.z, h2.z, c2); c2 = sdot8(w2.w, h2.w, c2);
      c3 = sdot8(w3.x, h3.x, c3); c3 = sdot8(w3.y, h3.y, c3);
      c3 = sdot8(w3.z, h3.z, c3); c3 = sdot8(w3.w, h3.w, c3);
    }
    int acc = (c0 + c1) + (c2 + c3);
    acc += __shfl_xor(acc, 1);

    int cr = min(max(acc, -32768), 32767);
    int ci = min(max(accin, -32768), 32767);
    float arg = __fadd_rn(__fmul_rn((float)cr, sr), __fmul_rn((float)ci, si));
    float hn = tanh_ref(arg);
    float hc = fminf(fmaxf(hn, -1.0f), 1.0f);
    int qv = (int)rintf(__fmul_rn(hc, 7.0f));

    // in-wave nibble pack (16 rows -> 1 dword per 16 lanes), publish ASAP
    unsigned nib = ((unsigned)qv & 15u) << (4 * ((lane >> 1) & 7));
    nib |= (unsigned)__shfl_xor((int)nib, 1);
    nib |= (unsigned)__shfl_xor((int)nib, 2);
    nib |= (unsigned)__shfl_xor((int)nib, 4);
    nib |= (unsigned)__shfl_xor((int)nib, 8);
    if ((lane & 15) == 0)
      publish_tag(hq2 + ((size_t)(nxt * 16 + b) * 256 + slice * 16 + wave * 4 + (lane >> 4)),
                  nib, (unsigned)(t + 1));

    // bf16 h history for deferred readout
    unsigned bfb = f2bf(hn);
    unsigned other = (unsigned)__shfl_xor((int)bfb, 2);
    if ((tid & 3) == 0)
      Hs[(size_t)(b * T_ + t) * (H_ / 2) + slice * 64 + (tid >> 2)] = bfb | (other << 16);

    ureg = unext;
  }
}

// ---- deferred readout: 512 blocks x 256 thr; 16 bt-rows x 64 v per block ---
#define ACC8(acc, p, w0, w1)                                    \
  acc = fmaf(__uint_as_float(p.x << 16), w0.x, acc);            \
  acc = fmaf(__uint_as_float(p.x & 0xffff0000u), w0.y, acc);    \
  acc = fmaf(__uint_as_float(p.y << 16), w0.z, acc);            \
  acc = fmaf(__uint_as_float(p.y & 0xffff0000u), w0.w, acc);    \
  acc = fmaf(__uint_as_float(p.z << 16), w1.x, acc);            \
  acc = fmaf(__uint_as_float(p.z & 0xffff0000u), w1.y, acc);    \
  acc = fmaf(__uint_as_float(p.w << 16), w1.z, acc);            \
  acc = fmaf(__uint_as_float(p.w & 0xffff0000u), w1.w, acc);

__global__ void __launch_bounds__(256) readout(const unsigned* __restrict__ Hs,
                                               const float* __restrict__ Wout,
                                               const float* __restrict__ Wb,
                                               float* __restrict__ out) {
  const int v = threadIdx.x & 63;
  const int rg = threadIdx.x >> 6;              // 0..3
  const int bt0 = blockIdx.x * 16 + rg * 4;     // 4 consecutive bt rows
  const float* wrow = Wout + (size_t)v * H_;
  const unsigned* h0 = Hs + (size_t)bt0 * (H_ / 2);
  float a0 = Wb[v], a1 = a0, a2 = a0, a3 = a0;
  for (int j = 0; j < H_ / 2; j += 4) {
    float4 w0 = *(const float4*)(wrow + 2 * j);
    float4 w1 = *(const float4*)(wrow + 2 * j + 4);
    uint4 p0 = *(const uint4*)(h0 + j);
    uint4 p1 = *(const uint4*)(h0 + (H_ / 2) + j);
    uint4 p2 = *(const uint4*)(h0 + 2 * (H_ / 2) + j);
    uint4 p3 = *(const uint4*)(h0 + 3 * (H_ / 2) + j);
    ACC8(a0, p0, w0, w1)
    ACC8(a1, p1, w0, w1)
    ACC8(a2, p2, w0, w1)
    ACC8(a3, p3, w0, w1)
  }
  out[(size_t)(bt0 + 0) * V_ + v] = a0;
  out[(size_t)(bt0 + 1) * V_ + v] = a1;
  out[(size_t)(bt0 + 2) * V_ + v] = a2;
  out[(size_t)(bt0 + 3) * V_ + v] = a3;
}

extern "C" void kernel_launch(void* const* d_in, const int* in_sizes, int n_in,
                              void* d_out, int out_size, void* d_ws, size_t ws_size,
                              hipStream_t stream) {
  const float* x = (const float*)d_in[0];
  const float* S_res = (const float*)d_in[1];
  const float* S_in = (const float*)d_in[2];
  const float* g_res = (const float*)d_in[3];
  const float* g_in = (const float*)d_in[4];
  const float* Woutw = (const float*)d_in[5];
  const float* Woutb = (const float*)d_in[6];
  const int* Wres = (const int*)d_in[7];
  const int* Win = (const int*)d_in[8];

  char* ws = (char*)d_ws;
  unsigned long long* hq2 = (unsigned long long*)(ws + 4096);  // 64 KiB tagged h
  int* um = (int*)(ws + (1 << 20));                            // 2 MiB
  int* ua = um + (1 << 19);                                    // 2 MiB
  int* wr4 = ua + (1 << 19);                                   // 2 MiB
  int* wi4 = wr4 + (1 << 19);                                  // 512 KiB
  unsigned* Hs = (unsigned*)(ws + (8 << 20));                  // 32 MiB bf16 h history

  hipMemsetAsync(d_ws, 0, 4096 + 65536, stream);  // hq2: h0 = 0, tag0 = 0
  hipLaunchKernelGGL(pack_weights, dim3(2560), dim3(256), 0, stream, Wres, Win, wr4, wi4);
  hipLaunchKernelGGL(pack_u, dim3(2048), dim3(256), 0, stream, x, um, ua);

  const int smem_bytes = 131072 + 1536;  // weights + h4/um/ua
  (void)hipFuncSetAttribute((const void*)esn_main, hipFuncAttributeMaxDynamicSharedMemorySize,
                            smem_bytes);

  float* outf = (float*)d_out;
  int t0 = 0, t1 = T_;
  void* args[] = {&um, &ua, &wr4, &wi4, &hq2, &S_res, &S_in,
                  &g_res, &g_in, &Hs, &t0, &t1};
  hipError_t e = hipLaunchCooperativeKernel((const void*)esn_main, dim3(NWG), dim3(NTHREADS),
                                            args, smem_bytes, stream);
  if (e != hipSuccess) {
    // fallback: one launch per timestep (kernel boundary = sync)
    for (int t = 0; t < T_; ++t) {
      hipLaunchKernelGGL(esn_main, dim3(NWG), dim3(NTHREADS), smem_bytes, stream,
                         um, ua, wr4, wi4, hq2, S_res, S_in, g_res, g_in, Hs, t, t + 1);
    }
  }
  hipLaunchKernelGGL(readout, dim3(B_ * T_ / 16), dim3(256), 0, stream,
                     Hs, Woutw, Woutb, outf);
}

// Round 5
// 1040.380 us; speedup vs baseline: 637.1156x; 1.0746x over previous
//
#include <hip/hip_runtime.h>
#include <hip/hip_bf16.h>

// ESN recurrence, B=16 T=512 F=512 H=2048 V=64.
// Integer matvecs exact (int4 packed, v_dot8_i32_i4). FP path replicates
// XLA/Eigen f32 tanh. 32 slice-WGs per batch (64 rows each) exchange h as
// tagged 8B {data,tag} units via relaxed agent-scope atomics (one L3 round
// trip per step). Weight slice lives in LDS; each step it is prefetched to
// registers via volatile-asm ds_read_b128 so the LDS stream overlaps the
// poll's observe window. Wave0-only polling + s_sleep backoff cuts L3
// contention. One barrier per step (u and h double-buffered).

#define B_ 16
#define T_ 512
#define F_ 512
#define H_ 2048
#define V_ 64
#define SLICES 32
#define RPW 64       // rows per workgroup
#define NTHREADS 256
#define NWG 512      // 16 batches x 32 slices

typedef int i4v __attribute__((ext_vector_type(4)));

#if defined(__has_builtin)
#if __has_builtin(__builtin_amdgcn_sdot8)
#define HAVE_SDOT8 1
#endif
#endif

__device__ __forceinline__ int sdot8(int a, int b, int c) {
#ifdef HAVE_SDOT8
  return __builtin_amdgcn_sdot8(a, b, c, false);
#else
#pragma unroll
  for (int i = 0; i < 8; ++i) {
    int av = (a << (28 - 4 * i)) >> 28;
    int bv = (b << (28 - 4 * i)) >> 28;
    c += av * bv;
  }
  return c;
#endif
}

// XLA / Eigen generic_fast_tanh_float, f32, fma form (bit-matching matters:
// quantized recurrence is chaotic at ULP level).
__device__ __forceinline__ float tanh_ref(float x) {
  float ax = fabsf(x);
  float xc = fminf(fmaxf(x, -7.90531110763549805f), 7.90531110763549805f);
  float x2 = __fmul_rn(xc, xc);
  float p = -2.76076847742355e-16f;
  p = __fmaf_rn(x2, p, 2.00018790482477e-13f);
  p = __fmaf_rn(x2, p, -8.60467152213735e-11f);
  p = __fmaf_rn(x2, p, 5.12229709037114e-08f);
  p = __fmaf_rn(x2, p, 1.48572235717979e-05f);
  p = __fmaf_rn(x2, p, 6.37261928875436e-04f);
  p = __fmaf_rn(x2, p, 4.89352455891786e-03f);
  p = __fmul_rn(xc, p);
  float q = 1.19825839466702e-06f;
  q = __fmaf_rn(x2, q, 1.18534705686654e-04f);
  q = __fmaf_rn(x2, q, 2.26843463243900e-03f);
  q = __fmaf_rn(x2, q, 4.89352518554385e-03f);
  float r = __fdiv_rn(p, q);
  return (ax < 0.0004f) ? x : r;
}

__device__ __forceinline__ unsigned f2bf(float f) {  // f32 -> bf16 bits, RNE
  unsigned u = __float_as_uint(f);
  return (u + 0x7fffu + ((u >> 16) & 1u)) >> 16;
}

__device__ __forceinline__ void publish_tag(unsigned long long* p, unsigned data, unsigned tag) {
  unsigned long long u = ((unsigned long long)tag << 32) | data;
  __hip_atomic_store(p, u, __ATOMIC_RELAXED, __HIP_MEMORY_SCOPE_AGENT);
}

// ---- prep: pack weights to int4 nibbles ------------------------------------
__global__ void pack_weights(const int* __restrict__ Wres, const int* __restrict__ Win,
                             int* __restrict__ wr4, int* __restrict__ wi4) {
  int id = blockIdx.x * blockDim.x + threadIdx.x;
  if (id < H_ * 256) {
    const int* src = Wres + id * 8;
    int pk = 0;
#pragma unroll
    for (int i = 0; i < 8; ++i) pk |= (src[i] & 15) << (4 * i);
    wr4[id] = pk;
  } else {
    int id2 = id - H_ * 256;
    if (id2 < H_ * 64) {
      const int* src = Win + id2 * 8;
      int pk = 0;
#pragma unroll
      for (int i = 0; i < 8; ++i) pk |= (src[i] & 15) << (4 * i);
      wi4[id2] = pk;
    }
  }
}

// ---- prep: quantize input, split u = 8*a + m into two int4 planes ----------
__global__ void pack_u(const float* __restrict__ x, int* __restrict__ um, int* __restrict__ ua) {
  int idx = blockIdx.x * blockDim.x + threadIdx.x;
  if (idx >= B_ * T_ * 64) return;
  const float* src = x + (size_t)idx * 8;
  int pm = 0, pa = 0;
#pragma unroll
  for (int i = 0; i < 8; ++i) {
    int u = (int)rintf(__fmul_rn(src[i], 3.0f));  // round-half-even == jnp.round
    int vv = u + 128;
    pm |= (vv & 7) << (4 * i);
    pa |= (((vv >> 3) - 16) & 15) << (4 * i);
  }
  um[idx] = pm;
  ua[idx] = pa;
}

// volatile-asm ds_read_b128: anchored issue point (scheduling-region
// boundary) so the 16 weight reads stay BEFORE the poll and drain during the
// observe window. Consumption fenced by __syncthreads (lgkmcnt 0) +
// sched_barrier(0).
#define WLD(i, OFFSTR) \
  asm volatile("ds_read_b128 %0, %1 offset:" OFFSTR : "=v"(wreg[i]) : "v"(lds_wb))

// ---- main persistent kernel ------------------------------------------------
__global__ void __launch_bounds__(NTHREADS, 2) esn_main(
    const int* __restrict__ um, const int* __restrict__ ua,
    const int* __restrict__ wr4, const int* __restrict__ wi4,
    unsigned long long* hq2,
    const float* __restrict__ S_res, const float* __restrict__ S_in,
    const float* __restrict__ g_res, const float* __restrict__ g_in,
    unsigned* __restrict__ Hs, int t0, int t1) {
  extern __shared__ __align__(16) char smem[];
  ::int4* lw4 = (::int4*)smem;                  // 16*256 int4 = 64 KiB
  int* lds_h = (int*)(lw4 + 16 * 256);          // 2 * 272 dw (68-dw quarter stride)
  int* lds_u = lds_h + 2 * 272;                 // 2 * 128 dw

  const int wg = blockIdx.x;
  const int b = wg & 15, slice = wg >> 4;       // slice 0..31
  const int tid = threadIdx.x;
  const unsigned lane = tid & 63;
  const int q = tid & 3;                        // quarter of K-range
  const int grow = slice * RPW + (tid >> 2);    // global row

  // one-time: W_res slice -> LDS (transposed: chunk m of all threads adjacent)
  {
    const ::int4* gw = (const ::int4*)wr4;  // 64 int4 per row
#pragma unroll 4
    for (int m = 0; m < 16; ++m) lw4[m * 256 + tid] = gw[grow * 64 + q * 16 + m];
  }
  // W_in quarter -> regs (4 int4, shared by both u planes)
  ::int4 rwm[4];
  {
    const ::int4* gwi = (const ::int4*)wi4;  // 16 int4 per row
#pragma unroll
    for (int m = 0; m < 4; ++m) rwm[m] = gwi[grow * 16 + q * 4 + m];
  }
  const float sr = __fmul_rn(__fdiv_rn(S_res[grow], 49.0f), g_res[0]);
  const float si = __fmul_rn(__fdiv_rn(S_in[grow], 21.0f), g_in[0]);

  const unsigned lds_wb = (unsigned)(size_t)smem + (unsigned)tid * 16u;

  // prologue: stage u_t0 into buf t0&1; prefetch u_{t0+1} into regs
  unsigned ureg = 0;
  if (tid < 128) {
    unsigned v0 = (tid < 64) ? (unsigned)um[(b * T_ + t0) * 64 + tid]
                             : (unsigned)ua[(b * T_ + t0) * 64 + (tid - 64)];
    lds_u[(t0 & 1) * 128 + tid] = (int)v0;
    if (t0 + 1 < T_)
      ureg = (tid < 64) ? (unsigned)um[(b * T_ + t0 + 1) * 64 + tid]
                        : (unsigned)ua[(b * T_ + t0 + 1) * 64 + (tid - 64)];
  }
  __syncthreads();

  for (int t = t0; t < t1; ++t) {
    const int cbuf = t & 1, nbuf = cbuf ^ 1;
    // 1. stage u_{t+1} into the opposite buffer (readers are next iter,
    //    separated by this iter's barrier)
    if (t + 1 < t1 && tid < 128) lds_u[nbuf * 128 + tid] = (int)ureg;

    // 2. input dot from lds_u[cbuf] (independent of h; off critical path)
    int am = 0, aa = 0;
    {
      const ::int4* lu = (const ::int4*)(lds_u + cbuf * 128);
#pragma unroll
      for (int m = 0; m < 4; ++m) {
        ::int4 w = rwm[m];
        ::int4 uM = lu[q * 4 + m];
        ::int4 uA = lu[16 + q * 4 + m];
        am = sdot8(w.x, uM.x, am); am = sdot8(w.y, uM.y, am);
        am = sdot8(w.z, uM.z, am); am = sdot8(w.w, uM.w, am);
        aa = sdot8(w.x, uA.x, aa); aa = sdot8(w.y, uA.y, aa);
        aa = sdot8(w.z, uA.z, aa); aa = sdot8(w.w, uA.w, aa);
      }
    }
    int accin = am + (aa << 3);
    accin += __shfl_xor(accin, 1);
    accin += __shfl_xor(accin, 2);

    // 3. issue the 16 weight ds_read_b128 (volatile asm, anchored pre-poll;
    //    they drain during the observe window)
    i4v wreg[16];
    WLD(0, "0");      WLD(1, "4096");   WLD(2, "8192");   WLD(3, "12288");
    WLD(4, "16384");  WLD(5, "20480");  WLD(6, "24576");  WLD(7, "28672");
    WLD(8, "32768");  WLD(9, "36864");  WLD(10, "40960"); WLD(11, "45056");
    WLD(12, "49152"); WLD(13, "53248"); WLD(14, "57344"); WLD(15, "61440");

    // 4. wave0: poll this batch's 256 tagged units (4 per thread) + stage h
    if (tid < 64) {
      const unsigned long long* p = hq2 + (size_t)(cbuf * 16 + b) * 256 + tid * 4;
      unsigned long long u0, u1, u2, u3;
      const unsigned tag = (unsigned)t;
      for (;;) {
        u0 = __hip_atomic_load(p + 0, __ATOMIC_RELAXED, __HIP_MEMORY_SCOPE_AGENT);
        u1 = __hip_atomic_load(p + 1, __ATOMIC_RELAXED, __HIP_MEMORY_SCOPE_AGENT);
        u2 = __hip_atomic_load(p + 2, __ATOMIC_RELAXED, __HIP_MEMORY_SCOPE_AGENT);
        u3 = __hip_atomic_load(p + 3, __ATOMIC_RELAXED, __HIP_MEMORY_SCOPE_AGENT);
        unsigned d = ((unsigned)(u0 >> 32) ^ tag) | ((unsigned)(u1 >> 32) ^ tag) |
                     ((unsigned)(u2 >> 32) ^ tag) | ((unsigned)(u3 >> 32) ^ tag);
        if (d == 0) break;
        __builtin_amdgcn_s_sleep(1);
      }
      ::int4 hv;
      hv.x = (int)u0; hv.y = (int)u1; hv.z = (int)u2; hv.w = (int)u3;
      ((::int4*)(lds_h + cbuf * 272))[(tid >> 4) * 17 + (tid & 15)] = hv;
    }

    // 5. barrier (lgkmcnt(0) drains weight reads + h write); fence VALU
    __syncthreads();
    __builtin_amdgcn_sched_barrier(0);

    // 6. recurrent dot: reg weights x conflict-free broadcast h, 4 chains
    int c0 = 0, c1 = 0, c2 = 0, c3 = 0;
    {
      const ::int4* lh = (const ::int4*)(lds_h + cbuf * 272);
#pragma unroll
      for (int m = 0; m < 16; m += 4) {
        ::int4 h0 = lh[q * 17 + m + 0];
        ::int4 h1 = lh[q * 17 + m + 1];
        ::int4 h2 = lh[q * 17 + m + 2];
        ::int4 h3 = lh[q * 17 + m + 3];
        c0 = sdot8(wreg[m + 0].x, h0.x, c0); c0 = sdot8(wreg[m + 0].y, h0.y, c0);
        c0 = sdot8(wreg[m + 0].z, h0.z, c0); c0 = sdot8(wreg[m + 0].w, h0.w, c0);
        c1 = sdot8(wreg[m + 1].x, h1.x, c1); c1 = sdot8(wreg[m + 1].y, h1.y, c1);
        c1 = sdot8(wreg[m + 1].z, h1.z, c1); c1 = sdot8(wreg[m + 1].w, h1.w, c1);
        c2 = sdot8(wreg[m + 2].x, h2.x, c2); c2 = sdot8(wreg[m + 2].y, h2.y, c2);
        c2 = sdot8(wreg[m + 2].z, h2.z, c2); c2 = sdot8(wreg[m + 2].w, h2.w, c2);
        c3 = sdot8(wreg[m + 3].x, h3.x, c3); c3 = sdot8(wreg[m + 3].y, h3.y, c3);
        c3 = sdot8(wreg[m + 3].z, h3.z, c3); c3 = sdot8(wreg[m + 3].w, h3.w, c3);
      }
    }
    int acc = (c0 + c1) + (c2 + c3);
    // 7. butterfly across the 4 quarter-lanes
    acc += __shfl_xor(acc, 1);
    acc += __shfl_xor(acc, 2);

    // 8. exact int16 saturation, scales, reference tanh, requantize
    int cr = min(max(acc, -32768), 32767);
    int ci = min(max(accin, -32768), 32767);
    float arg = __fadd_rn(__fmul_rn((float)cr, sr), __fmul_rn((float)ci, si));
    float hn = tanh_ref(arg);
    float hc = fminf(fmaxf(hn, -1.0f), 1.0f);
    int qv = (int)rintf(__fmul_rn(hc, 7.0f));

    // 9. pack 8 rows -> 1 dword per 32-lane half; publish ASAP
    unsigned nib = ((unsigned)qv & 15u) << (4 * ((lane >> 2) & 7));
    nib |= (unsigned)__shfl_xor((int)nib, 4);
    nib |= (unsigned)__shfl_xor((int)nib, 8);
    nib |= (unsigned)__shfl_xor((int)nib, 16);
    if ((lane & 31) == 0)
      publish_tag(hq2 + (size_t)((t ^ 1) & 1) * 0 +  // (readability no-op)
                      (size_t)(nbuf * 16 + b) * 256 + slice * 8 + (tid >> 6) * 2 + (lane >> 5),
                  nib, (unsigned)(t + 1));

    // 10. bf16 h history (pair rows) + next-u prefetch
    unsigned bfb = f2bf(hn);
    unsigned other = (unsigned)__shfl_xor((int)bfb, 4);
    if ((tid & 7) == 0)
      Hs[(size_t)(b * T_ + t) * (H_ / 2) + slice * 32 + (tid >> 3)] = bfb | (other << 16);
    if (t + 2 < T_ && tid < 128)
      ureg = (tid < 64) ? (unsigned)um[(b * T_ + t + 2) * 64 + tid]
                        : (unsigned)ua[(b * T_ + t + 2) * 64 + (tid - 64)];
  }
}

// ---- deferred readout: 512 blocks x 256 thr; 16 bt-rows x 64 v per block ---
#define ACC8(acc, p, w0, w1)                                    \
  acc = fmaf(__uint_as_float(p.x << 16), w0.x, acc);            \
  acc = fmaf(__uint_as_float(p.x & 0xffff0000u), w0.y, acc);    \
  acc = fmaf(__uint_as_float(p.y << 16), w0.z, acc);            \
  acc = fmaf(__uint_as_float(p.y & 0xffff0000u), w0.w, acc);    \
  acc = fmaf(__uint_as_float(p.z << 16), w1.x, acc);            \
  acc = fmaf(__uint_as_float(p.z & 0xffff0000u), w1.y, acc);    \
  acc = fmaf(__uint_as_float(p.w << 16), w1.z, acc);            \
  acc = fmaf(__uint_as_float(p.w & 0xffff0000u), w1.w, acc);

__global__ void __launch_bounds__(256) readout(const unsigned* __restrict__ Hs,
                                               const float* __restrict__ Wout,
                                               const float* __restrict__ Wb,
                                               float* __restrict__ out) {
  const int v = threadIdx.x & 63;
  const int rg = threadIdx.x >> 6;              // 0..3
  const int bt0 = blockIdx.x * 16 + rg * 4;     // 4 consecutive bt rows
  const float* wrow = Wout + (size_t)v * H_;
  const unsigned* h0 = Hs + (size_t)bt0 * (H_ / 2);
  float a0 = Wb[v], a1 = a0, a2 = a0, a3 = a0;
  for (int j = 0; j < H_ / 2; j += 4) {
    float4 w0 = *(const float4*)(wrow + 2 * j);
    float4 w1 = *(const float4*)(wrow + 2 * j + 4);
    uint4 p0 = *(const uint4*)(h0 + j);
    uint4 p1 = *(const uint4*)(h0 + (H_ / 2) + j);
    uint4 p2 = *(const uint4*)(h0 + 2 * (H_ / 2) + j);
    uint4 p3 = *(const uint4*)(h0 + 3 * (H_ / 2) + j);
    ACC8(a0, p0, w0, w1)
    ACC8(a1, p1, w0, w1)
    ACC8(a2, p2, w0, w1)
    ACC8(a3, p3, w0, w1)
  }
  out[(size_t)(bt0 + 0) * V_ + v] = a0;
  out[(size_t)(bt0 + 1) * V_ + v] = a1;
  out[(size_t)(bt0 + 2) * V_ + v] = a2;
  out[(size_t)(bt0 + 3) * V_ + v] = a3;
}

extern "C" void kernel_launch(void* const* d_in, const int* in_sizes, int n_in,
                              void* d_out, int out_size, void* d_ws, size_t ws_size,
                              hipStream_t stream) {
  const float* x = (const float*)d_in[0];
  const float* S_res = (const float*)d_in[1];
  const float* S_in = (const float*)d_in[2];
  const float* g_res = (const float*)d_in[3];
  const float* g_in = (const float*)d_in[4];
  const float* Woutw = (const float*)d_in[5];
  const float* Woutb = (const float*)d_in[6];
  const int* Wres = (const int*)d_in[7];
  const int* Win = (const int*)d_in[8];

  char* ws = (char*)d_ws;
  unsigned long long* hq2 = (unsigned long long*)(ws + 4096);  // 64 KiB tagged h
  int* um = (int*)(ws + (1 << 20));                            // 2 MiB
  int* ua = um + (1 << 19);                                    // 2 MiB
  int* wr4 = ua + (1 << 19);                                   // 2 MiB
  int* wi4 = wr4 + (1 << 19);                                  // 512 KiB
  unsigned* Hs = (unsigned*)(ws + (8 << 20));                  // 32 MiB bf16 h history

  hipMemsetAsync(d_ws, 0, 4096 + 65536, stream);  // hq2: h0 = 0, tag0 = 0
  hipLaunchKernelGGL(pack_weights, dim3(2560), dim3(256), 0, stream, Wres, Win, wr4, wi4);
  hipLaunchKernelGGL(pack_u, dim3(2048), dim3(256), 0, stream, x, um, ua);

  const int smem_bytes = 65536 + 2 * 272 * 4 + 2 * 128 * 4;  // 68736
  (void)hipFuncSetAttribute((const void*)esn_main, hipFuncAttributeMaxDynamicSharedMemorySize,
                            smem_bytes);

  int t0 = 0, t1 = T_;
  void* args[] = {&um, &ua, &wr4, &wi4, &hq2, &S_res, &S_in,
                  &g_res, &g_in, &Hs, &t0, &t1};
  hipError_t e = hipLaunchCooperativeKernel((const void*)esn_main, dim3(NWG), dim3(NTHREADS),
                                            args, smem_bytes, stream);
  if (e != hipSuccess) {
    // fallback: one launch per timestep (kernel boundary = sync)
    for (int t = 0; t < T_; ++t) {
      hipLaunchKernelGGL(esn_main, dim3(NWG), dim3(NTHREADS), smem_bytes, stream,
                         um, ua, wr4, wi4, hq2, S_res, S_in, g_res, g_in, Hs, t, t + 1);
    }
  }
  hipLaunchKernelGGL(readout, dim3(B_ * T_ / 16), dim3(256), 0, stream,
                     Hs, Woutw, Woutb, (float*)d_out);
}